// Round 6
// baseline (204.740 us; speedup 1.0000x reference)
//
#include <hip/hip_runtime.h>
#include <stdint.h>

// Problem constants (fixed by setup_inputs in the reference)
#define BATCH 32
#define HDIM  1024
#define WDIM  1024
#define H2    (HDIM / 2)
#define W2    (WDIM / 2)
#define NSTN  256                 // stations per batch
#define NBLOCKS 8192              // 4x4 px/thread: 8192*256*16px = 32*1024*1024

// clang native vectors. __builtin_nontemporal_load needs a native vector
// (HIP float4 is a class — invalid). The aligned(4) variant lets us do
// dword-aligned (unaligned-16) dwordx4 loads of the tgt window legally.
typedef float f32x4  __attribute__((ext_vector_type(4)));
typedef float f32x4u __attribute__((ext_vector_type(4), aligned(4)));

// ---------------------------------------------------------------------------
// Wave-64 + LDS block reduction (sum). Block size = 256. Result in thread 0.
// ---------------------------------------------------------------------------
__device__ __forceinline__ float blockReduceSum(float v, float* smem) {
    #pragma unroll
    for (int off = 32; off > 0; off >>= 1)
        v += __shfl_down(v, off, 64);
    const int lane = threadIdx.x & 63;
    const int wid  = threadIdx.x >> 6;
    if (lane == 0) smem[wid] = v;
    __syncthreads();
    v = (threadIdx.x < 4) ? smem[threadIdx.x] : 0.0f;
    if (wid == 0) {
        v += __shfl_down(v, 2, 64);
        v += __shfl_down(v, 1, 64);
    }
    return v;
}

// ---------------------------------------------------------------------------
// ROUND 6 — two row-pairs per thread (4 wide x 4 tall):
//   R3/R5 post-mortems: per-thread VMEM request count is the knob that has
//   moved the needle (21M reqs @ R5 -> fused ~40 us vs 27 us BW floor).
//   The 4-col tgt windows of adjacent row-pairs SHARE rows: pair yp=2q uses
//   tgt rows {2q-1,2q,2q+1}, pair yp=2q+1 uses {2q,2q+1,2q+2} -> only 4 tgt
//   row loads per thread instead of 6. Thread = 4 pred rows (4q..4q+3) x 4
//   cols + 4 tgt window loads = 8 VMEM / 16 px = 0.50/px (was 0.63), total
//   16.8M thread-requests (-20%), and HALF the waves (per-wave geometry +
//   reduction overhead amortized over 2x pixels; selcols 4 rows not 6).
//   ~62 VGPR -> launch_bounds(256,6) cap 85, no spill.
//
// tgt re-reads are L2/L3-resident; HBM traffic = pred 134 MB + tgt 34 MB
// = 168 MB -> 27 us floor at 6.3 TB/s.
//
// Chunked XCD swizzle kept (8192 = 8*1024, bijective).
//
// jax.image.resize 'bilinear' 512->1024 (half-pixel centers):
//   even y=2m:  0.25*t[m-1] + 0.75*t[m]   (index-clamped == edge renorm)
//   odd  y=2m+1: 0.75*t[m] + 0.25*t[m+1]  (same in x)
// ---------------------------------------------------------------------------

// Extract the 4-column window [m0-1 .. m0+2] (x-clamped) from the one
// dwordx4 loaded at tL. Three cases, all verified:
//  interior (tL=m0-1): L=[m0-1..m0+2]        -> (L.x, L.y, L.z, L.w)
//  isL (xg==0, tL=0):  L=[t0..t3], want (t0,t0,t1,t2)   -> (L.x,L.x,L.y,L.z)
//  isR (xg==255,tL=508): L=[508..511], want (509,510,511,511)
//                                            -> (L.y,L.z,L.w,L.w)
__device__ __forceinline__ void selcols(const f32x4u L, bool isL, bool isR,
                                        float c[4]) {
    c[0] = isR ? L.y : L.x;
    c[1] = isL ? L.x : (isR ? L.z : L.y);
    c[2] = isL ? L.y : (isR ? L.w : L.z);
    c[3] = isL ? L.z : L.w;
}

// Horizontal interp of the 4-col window t[] against 4 pred px + squared diff.
// px0 x=2m0  : 0.25t0+0.75t1 | px1: 0.75t1+0.25t2
// px2 x=2m0+2: 0.25t1+0.75t2 | px3: 0.75t2+0.25t3
__device__ __forceinline__ float rowLoss(const f32x4 p, const float t[4]) {
    const float u0 = 0.25f * t[0] + 0.75f * t[1];
    const float u1 = 0.75f * t[1] + 0.25f * t[2];
    const float u2 = 0.25f * t[1] + 0.75f * t[2];
    const float u3 = 0.75f * t[2] + 0.25f * t[3];
    const float d0 = p.x - u0, d1 = p.y - u1, d2 = p.z - u2, d3 = p.w - u3;
    return d0 * d0 + d1 * d1 + d2 * d2 + d3 * d3;
}

__global__ __launch_bounds__(256, 6) void fused_compute_kernel(
        const float* __restrict__ pred,
        const float* __restrict__ tgt,
        const int*   __restrict__ pos,
        const float* __restrict__ runoff,
        float* __restrict__ img_part,    // [NBLOCKS]
        float* __restrict__ stn_part) {  // [32]
    __shared__ float smem[4];

    // ---- station partial (blocks 0..31, one thread per station) ----
    if (blockIdx.x < 32) {
        const int idx = blockIdx.x * 256 + threadIdx.x;   // 32*256 = B*S
        const int bb = idx >> 8;                          // NSTN = 256
        const int px = pos[idx * 2 + 0];
        const int py = pos[idx * 2 + 1];
        const float* p = pred + ((int64_t)bb << 20);
        float sum = 0.0f; int cnt = 0;
        #pragma unroll
        for (int dy = -1; dy <= 1; ++dy) {
            const int y = py + dy;
            if (y < 0 || y >= HDIM) continue;
            #pragma unroll
            for (int dx = -1; dx <= 1; ++dx) {
                const int x = px + dx;
                if (x < 0 || x >= WDIM) continue;
                sum += p[y * WDIM + x];
                cnt++;
            }
        }
        const float d = sum / (float)cnt - runoff[idx];
        const float bs = blockReduceSum(d * d, smem);
        if (threadIdx.x == 0) stn_part[blockIdx.x] = bs;
        __syncthreads();   // smem reuse hazard before img reduction
    }

    // ---- image loss: ONE 4x4-px tile (two row-pairs) per thread ----
    // Chunked XCD swizzle: XCD j gets contiguous work ids [j*1024,(j+1)*1024)
    const int orig = blockIdx.x;
    const int w    = ((orig & 7) << 10) + (orig >> 3);  // bijective remap
    const int tid  = w * 256 + threadIdx.x;
    const int xg = tid & 255;            // 4-px x-group (wave: contiguous)
    const int q  = (tid >> 8) & 255;     // row-QUAD index (block-uniform)
    const int bb = tid >> 16;            // batch 0..31 (block-uniform)
    const int x0 = xg << 2;              // pred x
    const int m0 = xg << 1;              // tgt col of first even px

    const bool isL = (xg == 0);
    const bool isR = (xg == 255);
    const int tL = isL ? 0 : (isR ? (W2 - 4) : (m0 - 1));

    // pred rows 4q..4q+3 @ x0..x0+3 (nontemporal: zero-reuse 128 MB stream)
    const float* pr = pred + (bb << 20) + (q << 12) + x0;
    const f32x4 p0 = __builtin_nontemporal_load((const f32x4*)pr);
    const f32x4 p1 = __builtin_nontemporal_load((const f32x4*)(pr + WDIM));
    const f32x4 p2 = __builtin_nontemporal_load((const f32x4*)(pr + 2 * WDIM));
    const f32x4 p3 = __builtin_nontemporal_load((const f32x4*)(pr + 3 * WDIM));

    // tgt rows 2q-1, 2q, 2q+1, 2q+2 (y-clamped): one dwordx4 each at tL.
    // Pair yp=2q uses rows {r0,r1,r2}; pair yp=2q+1 uses {r1,r2,r3}.
    const int t0 = (q == 0)   ? 0   : 2 * q - 1;
    const int t3 = (q == 255) ? 511 : 2 * q + 2;
    const float* tb = tgt + (bb << 18);
    const f32x4u R0 = *(const f32x4u*)(tb + (t0 << 9)          + tL);
    const f32x4u R1 = *(const f32x4u*)(tb + ((2 * q) << 9)     + tL);
    const f32x4u R2 = *(const f32x4u*)(tb + ((2 * q + 1) << 9) + tL);
    const f32x4u R3 = *(const f32x4u*)(tb + (t3 << 9)          + tL);

    float a0[4], a1[4], a2[4], a3[4];
    selcols(R0, isL, isR, a0);
    selcols(R1, isL, isR, a1);
    selcols(R2, isL, isR, a2);
    selcols(R3, isL, isR, a3);

    // vertical interp: pair0 (pred rows 4q,4q+1), pair1 (pred rows 4q+2,4q+3)
    float e0[4], o0[4], e1[4], o1[4];
    #pragma unroll
    for (int j = 0; j < 4; ++j) {
        e0[j] = 0.25f * a0[j] + 0.75f * a1[j];
        o0[j] = 0.75f * a1[j] + 0.25f * a2[j];
        e1[j] = 0.25f * a1[j] + 0.75f * a2[j];
        o1[j] = 0.75f * a2[j] + 0.25f * a3[j];
    }

    const float img_local = rowLoss(p0, e0) + rowLoss(p1, o0)
                          + rowLoss(p2, e1) + rowLoss(p3, o1);

    const float bi = blockReduceSum(img_local, smem);
    if (threadIdx.x == 0) img_part[blockIdx.x] = bi;
}

// ---------------------------------------------------------------------------
// Kernel B: reduce 8192 img partials + 32 stn partials, write 3 outputs.
// ---------------------------------------------------------------------------
__global__ __launch_bounds__(256) void finalize_kernel(
        const float* __restrict__ img_part,
        const float* __restrict__ stn_part,
        float* __restrict__ out) {
    __shared__ float smem[4];

    // 8192 floats = 2048 float4; thread reads 8 coalesced float4s
    const f32x4* p4 = (const f32x4*)img_part;
    float v = 0.0f;
    #pragma unroll
    for (int i = 0; i < 8; ++i) {
        const f32x4 x = p4[threadIdx.x + i * 256];
        v += x.x + x.y + x.z + x.w;
    }
    const float img_sum = blockReduceSum(v, smem);
    __syncthreads();   // smem reuse

    float s = (threadIdx.x < 32) ? stn_part[threadIdx.x] : 0.0f;
    const float stn_sum = blockReduceSum(s, smem);

    if (threadIdx.x == 0) {
        const float img = img_sum * (1.0f / ((float)BATCH * HDIM * WDIM));
        const float stn = stn_sum * (1.0f / ((float)BATCH * NSTN));
        out[0] = img + 0.5f * stn;   // IMAGE_W=1.0, STATION_W=0.5
        out[1] = img;
        out[2] = stn;
    }
}

extern "C" void kernel_launch(void* const* d_in, const int* in_sizes, int n_in,
                              void* d_out, int out_size, void* d_ws, size_t ws_size,
                              hipStream_t stream) {
    const float* pred   = (const float*)d_in[0];
    const float* tgt    = (const float*)d_in[1];
    const int*   pos    = (const int*)d_in[2];
    const float* runoff = (const float*)d_in[3];
    float* out = (float*)d_out;
    float* img_part = (float*)d_ws;            // [NBLOCKS]
    float* stn_part = img_part + NBLOCKS;      // [32]

    // No memset needed: every partial slot is written unconditionally.
    fused_compute_kernel<<<NBLOCKS, 256, 0, stream>>>(pred, tgt, pos, runoff,
                                                      img_part, stn_part);
    finalize_kernel<<<1, 256, 0, stream>>>(img_part, stn_part, out);
}